// Round 2
// baseline (3270.632 us; speedup 1.0000x reference)
//
#include <hip/hip_runtime.h>
#include <hip/hip_bf16.h>
#include <cstdint>

// ---------------------------------------------------------------------------
// SplineNet forward on gfx950.
// Pipeline:
//   1. CSR build: deg histogram -> block scan -> edge scatter (sorted by dst)
//   2. Per layer: acc_kernel (wave-per-node, T_n[25][32] in LDS via ds_add,
//                 two-phase: lane-parallel edge metadata + pipelined X loads)
//                 -> chunked global T -> gemm_kernel [64 x COUT] tiles with
//                 fused /deg + root + bias + relu epilogue
//   3. pool_kernel (binary search over sorted batch) + head_kernel (gated MLP)
// ---------------------------------------------------------------------------

__device__ __forceinline__ int lowb(const int* __restrict__ a, int n, int v) {
  int lo = 0, hi = n;
  while (lo < hi) { int m = (lo + hi) >> 1; if (a[m] < v) lo = m + 1; else hi = m; }
  return lo;
}

__global__ void hist_kernel(const int* __restrict__ dst, int E, int* __restrict__ deg) {
  int e = blockIdx.x * 256 + threadIdx.x;
  if (e < E) atomicAdd(&deg[dst[e]], 1);
}

// Inclusive scan within blocks of 1024; writes offs[gi+1], block totals to bsums.
__global__ __launch_bounds__(1024) void scan_block_kernel(
    const int* __restrict__ deg, int n, int* __restrict__ offs, int* __restrict__ bsums) {
  __shared__ int wsum[16];
  int t = threadIdx.x;
  int gi = blockIdx.x * 1024 + t;
  int v = (gi < n) ? deg[gi] : 0;
  int lane = t & 63, w = t >> 6;
  int x = v;
  #pragma unroll
  for (int d = 1; d < 64; d <<= 1) { int y = __shfl_up(x, d, 64); if (lane >= d) x += y; }
  if (lane == 63) wsum[w] = x;
  __syncthreads();
  if (w == 0) {
    int s = (lane < 16) ? wsum[lane] : 0;
    #pragma unroll
    for (int d = 1; d < 16; d <<= 1) { int y = __shfl_up(s, d, 64); if (lane >= d) s += y; }
    if (lane < 16) wsum[lane] = s;
  }
  __syncthreads();
  int add = (w > 0) ? wsum[w - 1] : 0;
  x += add;
  if (gi < n) offs[gi + 1] = x;
  if (t == 1023) bsums[blockIdx.x] = x;
}

__global__ __launch_bounds__(64) void scan_bsums_kernel(
    const int* __restrict__ bsums, int nb, int* __restrict__ boff) {
  int l = threadIdx.x;
  int v = (l < nb) ? bsums[l] : 0;
  int x = v;
  #pragma unroll
  for (int d = 1; d < 64; d <<= 1) { int y = __shfl_up(x, d, 64); if (l >= d) x += y; }
  if (l < nb) boff[l] = x - v;   // exclusive
}

__global__ void scan_add_kernel(int* __restrict__ offs, const int* __restrict__ boff, int n) {
  int i = blockIdx.x * 256 + threadIdx.x;
  if (i < n) offs[i + 1] += boff[i >> 10];
  if (i == 0) offs[0] = 0;
}

__global__ void scatter_kernel(const int* __restrict__ src, const int* __restrict__ dst, int E,
                               const int* __restrict__ offs, int* __restrict__ cursor,
                               int2* __restrict__ recs) {
  int e = blockIdx.x * 256 + threadIdx.x;
  if (e < E) {
    int d = dst[e];
    int p = offs[d] + atomicAdd(&cursor[d], 1);
    recs[p] = make_int2(src[e], e);
  }
}

// Wave-per-node accumulation of T_n[25][32] in LDS, streamed to global T chunk.
// Phase A: lane-parallel metadata for a 64-edge batch (coalesced recs, parallel
// attr loads). Phase B: per-edge scatter; metadata via __shfl broadcast, X-row
// loads software-pipelined 8-deep.
__global__ __launch_bounds__(512) void acc_kernel(
    const int2* __restrict__ recs, const int* __restrict__ offs,
    const float2* __restrict__ attr, const float* __restrict__ X,
    float* __restrict__ T, int c0, int nEnd) {
  __shared__ float Tld[8][800];
  const int w = threadIdx.x >> 6;
  const int lane = threadIdx.x & 63;
  const int n = c0 + blockIdx.x * 8 + w;
  if (n >= nEnd) return;                    // no barriers in this kernel
  for (int j = lane; j < 800; j += 64) Tld[w][j] = 0.f;
  const int beg = offs[n];
  const int end = offs[n + 1];
  const int i = lane & 63 & 31;
  const int h = lane >> 5;
  for (int b0 = beg; b0 < end; b0 += 64) {
    const int cnt = (end - b0 < 64) ? (end - b0) : 64;
    // --- Phase A: lane l holds metadata for edge b0+l (clamped in-range) ---
    int e = b0 + (lane < cnt ? lane : cnt - 1);
    int2 r = recs[e];
    float2 a = attr[r.y];
    float v0 = a.x * 4.f, v1 = a.y * 4.f;
    float l0 = floorf(v0), l1 = floorf(v1);
    float myF0 = v0 - l0;
    float myF1 = v1 - l1;
    int i00 = min((int)l0, 4);
    int i10 = min((int)l1, 4);
    int myPack = i00 | (i10 << 8);
    int mySrc = r.x;
    // --- Phase B: edge-serial scatter, 8-deep pipelined X loads ---
    for (int j0 = 0; j0 < cnt; j0 += 8) {
      float xv[8], wA[8], wB[8];
      int aA[8], aB[8];
      #pragma unroll
      for (int u = 0; u < 8; ++u) {
        int j = j0 + u;
        int jc = (j < cnt) ? j : (cnt - 1);
        int   src = __shfl(mySrc, jc);
        float f0  = __shfl(myF0, jc);
        float f1  = __shfl(myF1, jc);
        int   pk  = __shfl(myPack, jc);
        int i00e = pk & 0xff;
        int i10e = (pk >> 8) & 0xff;
        int i01e = min(i00e + 1, 4);
        int i11e = min(i10e + 1, 4);
        float b1d = h ? f1 : (1.f - f1);
        if (j >= cnt) b1d = 0.f;            // wave-uniform predicate
        int k1 = h ? i11e : i10e;
        int basea = k1 * 160 + i;
        aA[u] = basea + i00e * 32;
        aB[u] = basea + i01e * 32;
        wA[u] = (1.f - f0) * b1d;
        wB[u] = f0 * b1d;
        xv[u] = X[(size_t)src * 32 + i];
      }
      #pragma unroll
      for (int u = 0; u < 8; ++u) {
        atomicAdd(&Tld[w][aA[u]], wA[u] * xv[u]);
        atomicAdd(&Tld[w][aB[u]], wB[u] * xv[u]);
      }
    }
  }
  float4* Tg = (float4*)(T + (size_t)(n - c0) * 800);
  #pragma unroll
  for (int q = 0; q < 4; ++q) {
    int j4 = q * 64 + lane;
    if (j4 < 200) Tg[j4] = *(const float4*)&Tld[w][j4 * 4];
  }
}

// Tiled GEMM: out[64 x COUT] = T[64 x 800] @ W[800 x COUT], fused epilogue:
// acc /= max(deg,1); acc += X[64 x 32] @ root[32 x COUT]; + bias; relu; store.
template <int COUT>
__global__ __launch_bounds__(256) void gemm_kernel(
    const float* __restrict__ T, const float* __restrict__ W,
    const float* __restrict__ X, const float* __restrict__ root,
    const float* __restrict__ bias, const int* __restrict__ deg,
    float* __restrict__ H, int c0, int Nvalid) {
  constexpr int NB = COUT / 16;             // 2 (COUT=32) or 4 (COUT=64)
  __shared__ float As[32 * 68];             // [BK=32][64 + pad4], 16B-aligned cols
  __shared__ float Bs[32 * COUT];
  const int t = threadIdx.x;
  const int tm = t & 15, tn = t >> 4;
  const int mBase = blockIdx.x * 64;
  float acc[4][NB];
  #pragma unroll
  for (int a = 0; a < 4; ++a)
    #pragma unroll
    for (int b = 0; b < NB; ++b) acc[a][b] = 0.f;

  for (int k0 = 0; k0 < 800; k0 += 32) {
    #pragma unroll
    for (int q = 0; q < 2; ++q) {           // stage A transposed
      int idx = q * 256 + t;
      int row = idx >> 3, kq = idx & 7;
      float4 v = *(const float4*)&T[(size_t)(mBase + row) * 800 + k0 + kq * 4];
      As[(kq * 4 + 0) * 68 + row] = v.x;
      As[(kq * 4 + 1) * 68 + row] = v.y;
      As[(kq * 4 + 2) * 68 + row] = v.z;
      As[(kq * 4 + 3) * 68 + row] = v.w;
    }
    #pragma unroll
    for (int q = 0; q < (32 * COUT) / 1024; ++q) {  // stage B row-major
      int idx = q * 256 + t;
      *(float4*)&Bs[idx * 4] = *(const float4*)&W[k0 * COUT + idx * 4];
    }
    __syncthreads();
    #pragma unroll
    for (int kk = 0; kk < 32; ++kk) {
      float4 av = *(const float4*)&As[kk * 68 + tm * 4];
      float bv[NB];
      if constexpr (COUT == 32) {
        float2 b2 = *(const float2*)&Bs[kk * 32 + tn * 2];
        bv[0] = b2.x; bv[1] = b2.y;
      } else {
        float4 b4 = *(const float4*)&Bs[kk * 64 + tn * 4];
        bv[0] = b4.x; bv[1] = b4.y; bv[2] = b4.z; bv[3] = b4.w;
      }
      const float am[4] = {av.x, av.y, av.z, av.w};
      #pragma unroll
      for (int mi = 0; mi < 4; ++mi)
        #pragma unroll
        for (int nj = 0; nj < NB; ++nj)
          acc[mi][nj] = fmaf(am[mi], bv[nj], acc[mi][nj]);
    }
    __syncthreads();
  }
  // mean (deg) applies only to the aggregated part
  #pragma unroll
  for (int mi = 0; mi < 4; ++mi) {
    int m = c0 + mBase + tm * 4 + mi;
    float rd = 1.f / (float)max(deg[m], 1);
    #pragma unroll
    for (int nj = 0; nj < NB; ++nj) acc[mi][nj] *= rd;
  }
  // root phase: one BK=32 pass with A=X rows, B=root
  {
    #pragma unroll
    for (int q = 0; q < 2; ++q) {
      int idx = q * 256 + t;
      int row = idx >> 3, kq = idx & 7;
      int gr = min(c0 + mBase + row, Nvalid - 1);
      float4 v = *(const float4*)&X[(size_t)gr * 32 + kq * 4];
      As[(kq * 4 + 0) * 68 + row] = v.x;
      As[(kq * 4 + 1) * 68 + row] = v.y;
      As[(kq * 4 + 2) * 68 + row] = v.z;
      As[(kq * 4 + 3) * 68 + row] = v.w;
    }
    #pragma unroll
    for (int q = 0; q < (32 * COUT) / 1024; ++q) {
      int idx = q * 256 + t;
      *(float4*)&Bs[idx * 4] = *(const float4*)&root[idx * 4];
    }
    __syncthreads();
    #pragma unroll
    for (int kk = 0; kk < 32; ++kk) {
      float4 av = *(const float4*)&As[kk * 68 + tm * 4];
      float bv[NB];
      if constexpr (COUT == 32) {
        float2 b2 = *(const float2*)&Bs[kk * 32 + tn * 2];
        bv[0] = b2.x; bv[1] = b2.y;
      } else {
        float4 b4 = *(const float4*)&Bs[kk * 64 + tn * 4];
        bv[0] = b4.x; bv[1] = b4.y; bv[2] = b4.z; bv[3] = b4.w;
      }
      const float am[4] = {av.x, av.y, av.z, av.w};
      #pragma unroll
      for (int mi = 0; mi < 4; ++mi)
        #pragma unroll
        for (int nj = 0; nj < NB; ++nj)
          acc[mi][nj] = fmaf(am[mi], bv[nj], acc[mi][nj]);
    }
  }
  float bv[NB];
  #pragma unroll
  for (int nj = 0; nj < NB; ++nj) bv[nj] = bias[tn * NB + nj];
  #pragma unroll
  for (int mi = 0; mi < 4; ++mi) {
    int m = c0 + mBase + tm * 4 + mi;
    if (m < Nvalid) {
      if constexpr (COUT == 32) {
        float2 o;
        o.x = fmaxf(acc[mi][0] + bv[0], 0.f);
        o.y = fmaxf(acc[mi][1] + bv[1], 0.f);
        *(float2*)&H[(size_t)m * 32 + tn * 2] = o;
      } else {
        float4 o;
        o.x = fmaxf(acc[mi][0] + bv[0], 0.f);
        o.y = fmaxf(acc[mi][1] + bv[1], 0.f);
        o.z = fmaxf(acc[mi][2] + bv[2], 0.f);
        o.w = fmaxf(acc[mi][3] + bv[3], 0.f);
        *(float4*)&H[(size_t)m * 64 + tn * 4] = o;
      }
    }
  }
}

__global__ __launch_bounds__(256) void pool_kernel(
    const float* __restrict__ h2, const int* __restrict__ batch, int N,
    float* __restrict__ poolacc) {
  __shared__ float red[4][64];
  int g = blockIdx.x >> 2, part = blockIdx.x & 3;
  int lo = lowb(batch, N, g), hi = lowb(batch, N, g + 1);
  int len = hi - lo;
  int b0 = lo + (int)(((long long)len * part) / 4);
  int b1 = lo + (int)(((long long)len * (part + 1)) / 4);
  int r = threadIdx.x >> 6, o = threadIdx.x & 63;
  float s = 0.f;
  for (int row = b0 + r; row < b1; row += 4) s += h2[(size_t)row * 64 + o];
  red[r][o] = s;
  __syncthreads();
  if (r == 0) {
    float v = red[0][o] + red[1][o] + red[2][o] + red[3][o];
    atomicAdd(&poolacc[g * 64 + o], v);
  }
}

__global__ __launch_bounds__(64) void head_kernel(
    const float* __restrict__ poolacc, const int* __restrict__ batch, int N,
    const float* __restrict__ w1, const float* __restrict__ b1,
    const float* __restrict__ w2, const float* __restrict__ b2,
    const float* __restrict__ w3, const float* __restrict__ b3,
    float* __restrict__ out) {
  __shared__ float gb[64];
  __shared__ float lg[10];
  int g = blockIdx.x, o = threadIdx.x;
  int lo = lowb(batch, N, g), hi = lowb(batch, N, g + 1);
  float cnt = fmaxf((float)(hi - lo), 1.f);
  float gv = poolacc[g * 64 + o] / cnt;
  gb[o] = gv;
  __syncthreads();
  float tacc = b1[o];
  for (int i = 0; i < 64; ++i) tacc = fmaf(gb[i], w1[i * 64 + o], tacc);
  gv = gv * (1.f / (1.f + expf(-tacc)));
  __syncthreads(); gb[o] = gv; __syncthreads();
  tacc = b2[o];
  for (int i = 0; i < 64; ++i) tacc = fmaf(gb[i], w2[i * 64 + o], tacc);
  gv = gv * (1.f / (1.f + expf(-tacc)));
  __syncthreads(); gb[o] = gv; __syncthreads();
  if (o < 10) {
    float l = b3[o];
    for (int i = 0; i < 64; ++i) l = fmaf(gb[i], w3[i * 10 + o], l);
    lg[o] = l;
  }
  __syncthreads();
  if (o < 10) {
    float m = lg[0];
    #pragma unroll
    for (int c = 1; c < 10; ++c) m = fmaxf(m, lg[c]);
    float s = 0.f;
    #pragma unroll
    for (int c = 0; c < 10; ++c) s += expf(lg[c] - m);
    out[g * 10 + o] = lg[o] - m - logf(s);
  }
}

extern "C" void kernel_launch(void* const* d_in, const int* in_sizes, int n_in,
                              void* d_out, int out_size, void* d_ws, size_t ws_size,
                              hipStream_t stream) {
  const float* x     = (const float*)d_in[0];
  const int*   ei    = (const int*)d_in[1];
  const float* eattr = (const float*)d_in[2];
  const int*   batch = (const int*)d_in[3];
  const float* W1    = (const float*)d_in[4];
  const float* root1 = (const float*)d_in[5];
  const float* b1    = (const float*)d_in[6];
  const float* W2    = (const float*)d_in[7];
  const float* root2 = (const float*)d_in[8];
  const float* b2    = (const float*)d_in[9];
  const float* l1w   = (const float*)d_in[10];
  const float* l1b   = (const float*)d_in[11];
  const float* l2w   = (const float*)d_in[12];
  const float* l2b   = (const float*)d_in[13];
  const float* l3w   = (const float*)d_in[14];
  const float* l3b   = (const float*)d_in[15];
  float* out = (float*)d_out;

  const int N = in_sizes[0] / 32;
  const int E = in_sizes[1] / 2;
  const int Npad = (N + 63) & ~63;

  char* base = (char*)d_ws;
  size_t off = 0;
  auto walloc = [&](size_t bytes) -> void* {
    off = (off + 255) & ~(size_t)255;
    void* p = base + off;
    off += bytes;
    return p;
  };
  int*   deg     = (int*)walloc((size_t)Npad * 4);
  int*   offs    = (int*)walloc((size_t)(N + 1) * 4);
  int*   cursor  = (int*)walloc((size_t)N * 4);
  int*   bsums   = (int*)walloc(64 * 4);
  int*   boff    = (int*)walloc(64 * 4);
  float* poolacc = (float*)walloc(64 * 64 * 4);
  float* h1      = (float*)walloc((size_t)N * 32 * 4);
  float* h2      = (float*)walloc((size_t)N * 64 * 4);
  int2*  recs    = (int2*)walloc((size_t)E * 8);
  off = (off + 255) & ~(size_t)255;
  size_t remain = (ws_size > off) ? (ws_size - off) : 0;
  int chunkRows = (int)(remain / (800 * 4));
  chunkRows &= ~63;
  if (chunkRows > 12800) chunkRows = 12800;
  if (chunkRows > Npad) chunkRows = Npad;
  if (chunkRows < 64) return;               // insufficient workspace
  float* T = (float*)(base + off);

  const int* srcA = ei;
  const int* dstA = ei + E;

  hipMemsetAsync(deg, 0, (size_t)Npad * 4, stream);
  hipMemsetAsync(cursor, 0, (size_t)N * 4, stream);
  hipMemsetAsync(poolacc, 0, 64 * 64 * 4, stream);

  hist_kernel<<<(E + 255) / 256, 256, 0, stream>>>(dstA, E, deg);
  int nb = (N + 1023) / 1024;
  scan_block_kernel<<<nb, 1024, 0, stream>>>(deg, N, offs, bsums);
  scan_bsums_kernel<<<1, 64, 0, stream>>>(bsums, nb, boff);
  scan_add_kernel<<<(N + 255) / 256, 256, 0, stream>>>(offs, boff, N);
  scatter_kernel<<<(E + 255) / 256, 256, 0, stream>>>(srcA, dstA, E, offs, cursor, recs);

  for (int layer = 0; layer < 2; ++layer) {
    const float* Xin = layer ? h1 : x;
    const float* Wl  = layer ? W2 : W1;
    const float* rl  = layer ? root2 : root1;
    const float* bl  = layer ? b2 : b1;
    float* Hout      = layer ? h2 : h1;
    for (int c0 = 0; c0 < N; c0 += chunkRows) {
      int cn = (chunkRows < N - c0) ? chunkRows : (N - c0);
      int accBlocks = (cn + 7) / 8;
      acc_kernel<<<accBlocks, 512, 0, stream>>>(recs, offs, (const float2*)eattr,
                                                Xin, T, c0, c0 + cn);
      int tiles = (cn + 63) / 64;
      if (layer == 0)
        gemm_kernel<32><<<tiles, 256, 0, stream>>>(T, Wl, Xin, rl, bl, deg, Hout, c0, N);
      else
        gemm_kernel<64><<<tiles, 256, 0, stream>>>(T, Wl, Xin, rl, bl, deg, Hout, c0, N);
    }
  }
  pool_kernel<<<256, 256, 0, stream>>>(h2, batch, N, poolacc);
  head_kernel<<<64, 64, 0, stream>>>(poolacc, batch, N,
                                     l1w, l1b, l2w, l2b, l3w, l3b, out);
}

// Round 3
// 2880.829 us; speedup vs baseline: 1.1353x; 1.1353x over previous
//
#include <hip/hip_runtime.h>
#include <hip/hip_bf16.h>
#include <cstdint>

// ---------------------------------------------------------------------------
// SplineNet forward on gfx950.
// Pipeline:
//   1. CSR build: deg histogram -> block scan -> edge scatter (sorted by dst)
//   2. Per layer: acc_kernel (wave-per-node; LANE-PER-EDGE: each lane loads its
//                 own rec/attr/X-row -> 64 independent miss chains in flight;
//                 scatters via ds atomics into the node's LDS tile, chunk-
//                 rotated to cap bank aliasing at ~8-way)
//                 -> chunked global T -> gemm_kernel [64 x COUT] tiles with
//                 fused /deg + root + bias + relu epilogue
//   3. pool_kernel (binary search over sorted batch) + head_kernel (gated MLP)
// ---------------------------------------------------------------------------

__device__ __forceinline__ int lowb(const int* __restrict__ a, int n, int v) {
  int lo = 0, hi = n;
  while (lo < hi) { int m = (lo + hi) >> 1; if (a[m] < v) lo = m + 1; else hi = m; }
  return lo;
}

__global__ void hist_kernel(const int* __restrict__ dst, int E, int* __restrict__ deg) {
  int e = blockIdx.x * 256 + threadIdx.x;
  if (e < E) atomicAdd(&deg[dst[e]], 1);
}

// Inclusive scan within blocks of 1024; writes offs[gi+1], block totals to bsums.
__global__ __launch_bounds__(1024) void scan_block_kernel(
    const int* __restrict__ deg, int n, int* __restrict__ offs, int* __restrict__ bsums) {
  __shared__ int wsum[16];
  int t = threadIdx.x;
  int gi = blockIdx.x * 1024 + t;
  int v = (gi < n) ? deg[gi] : 0;
  int lane = t & 63, w = t >> 6;
  int x = v;
  #pragma unroll
  for (int d = 1; d < 64; d <<= 1) { int y = __shfl_up(x, d, 64); if (lane >= d) x += y; }
  if (lane == 63) wsum[w] = x;
  __syncthreads();
  if (w == 0) {
    int s = (lane < 16) ? wsum[lane] : 0;
    #pragma unroll
    for (int d = 1; d < 16; d <<= 1) { int y = __shfl_up(s, d, 64); if (lane >= d) s += y; }
    if (lane < 16) wsum[lane] = s;
  }
  __syncthreads();
  int add = (w > 0) ? wsum[w - 1] : 0;
  x += add;
  if (gi < n) offs[gi + 1] = x;
  if (t == 1023) bsums[blockIdx.x] = x;
}

__global__ __launch_bounds__(64) void scan_bsums_kernel(
    const int* __restrict__ bsums, int nb, int* __restrict__ boff) {
  int l = threadIdx.x;
  int v = (l < nb) ? bsums[l] : 0;
  int x = v;
  #pragma unroll
  for (int d = 1; d < 64; d <<= 1) { int y = __shfl_up(x, d, 64); if (l >= d) x += y; }
  if (l < nb) boff[l] = x - v;   // exclusive
}

__global__ void scan_add_kernel(int* __restrict__ offs, const int* __restrict__ boff, int n) {
  int i = blockIdx.x * 256 + threadIdx.x;
  if (i < n) offs[i + 1] += boff[i >> 10];
  if (i == 0) offs[0] = 0;
}

__global__ void scatter_kernel(const int* __restrict__ src, const int* __restrict__ dst, int E,
                               const int* __restrict__ offs, int* __restrict__ cursor,
                               int2* __restrict__ recs) {
  int e = blockIdx.x * 256 + threadIdx.x;
  if (e < E) {
    int d = dst[e];
    int p = offs[d] + atomicAdd(&cursor[d], 1);
    recs[p] = make_int2(src[e], e);
  }
}

// Wave-per-node accumulation of T_n[25][32] in LDS; lane-per-edge.
// Each lane: load rec (coalesced) + attr (1-line gather) + its X row as 8
// float4 chunks in lane-rotated order; 4 ds atomics per channel into the
// node tile. Rotation keeps bank aliasing ~8-way instead of 64-way.
__global__ __launch_bounds__(512) void acc_kernel(
    const int2* __restrict__ recs, const int* __restrict__ offs,
    const float2* __restrict__ attr, const float* __restrict__ X,
    float* __restrict__ T, int c0, int nEnd) {
  __shared__ float Tld[8][800];
  const int w = threadIdx.x >> 6;
  const int lane = threadIdx.x & 63;
  const int n = c0 + blockIdx.x * 8 + w;
  if (n >= nEnd) return;                    // no barriers in this kernel
  for (int j = lane; j < 800; j += 64) Tld[w][j] = 0.f;
  const int beg = offs[n];
  const int end = offs[n + 1];
  const int rot = lane & 7;
  for (int e0 = beg; e0 < end; e0 += 64) {
    int e = e0 + lane;
    if (e < end) {
      int2 r = recs[e];
      float2 a = attr[r.y];
      float v0 = a.x * 4.f, v1 = a.y * 4.f;
      float l0 = floorf(v0), l1 = floorf(v1);
      float f0 = v0 - l0, f1 = v1 - l1;
      int i00 = min((int)l0, 4); int i01 = min(i00 + 1, 4);
      int i10 = min((int)l1, 4); int i11 = min(i10 + 1, 4);
      float w00 = (1.f - f0) * (1.f - f1);
      float w10 = f0 * (1.f - f1);
      float w01 = (1.f - f0) * f1;
      float w11 = f0 * f1;
      int s00 = (i00 + 5 * i10) * 32;
      int s10 = (i01 + 5 * i10) * 32;
      int s01 = (i00 + 5 * i11) * 32;
      int s11 = (i01 + 5 * i11) * 32;
      const float* xrow = X + (size_t)r.x * 32;
      #pragma unroll
      for (int q = 0; q < 8; ++q) {
        int qq = (q + rot) & 7;             // lane-rotated chunk order
        float4 v = *(const float4*)(xrow + qq * 4);
        #pragma unroll
        for (int el = 0; el < 4; ++el) {
          int ch = qq * 4 + el;
          float xv = (&v.x)[el];            // static element index
          atomicAdd(&Tld[w][s00 + ch], w00 * xv);
          atomicAdd(&Tld[w][s10 + ch], w10 * xv);
          atomicAdd(&Tld[w][s01 + ch], w01 * xv);
          atomicAdd(&Tld[w][s11 + ch], w11 * xv);
        }
      }
    }
  }
  float4* Tg = (float4*)(T + (size_t)(n - c0) * 800);
  #pragma unroll
  for (int q = 0; q < 4; ++q) {
    int j4 = q * 64 + lane;
    if (j4 < 200) Tg[j4] = *(const float4*)&Tld[w][j4 * 4];
  }
}

// Tiled GEMM: out[64 x COUT] = T[64 x 800] @ W[800 x COUT], fused epilogue:
// acc /= max(deg,1); acc += X[64 x 32] @ root[32 x COUT]; + bias; relu; store.
template <int COUT>
__global__ __launch_bounds__(256) void gemm_kernel(
    const float* __restrict__ T, const float* __restrict__ W,
    const float* __restrict__ X, const float* __restrict__ root,
    const float* __restrict__ bias, const int* __restrict__ deg,
    float* __restrict__ H, int c0, int Nvalid) {
  constexpr int NB = COUT / 16;             // 2 (COUT=32) or 4 (COUT=64)
  __shared__ float As[32 * 68];             // [BK=32][64 + pad4], 16B-aligned cols
  __shared__ float Bs[32 * COUT];
  const int t = threadIdx.x;
  const int tm = t & 15, tn = t >> 4;
  const int mBase = blockIdx.x * 64;
  float acc[4][NB];
  #pragma unroll
  for (int a = 0; a < 4; ++a)
    #pragma unroll
    for (int b = 0; b < NB; ++b) acc[a][b] = 0.f;

  for (int k0 = 0; k0 < 800; k0 += 32) {
    #pragma unroll
    for (int q = 0; q < 2; ++q) {           // stage A transposed
      int idx = q * 256 + t;
      int row = idx >> 3, kq = idx & 7;
      float4 v = *(const float4*)&T[(size_t)(mBase + row) * 800 + k0 + kq * 4];
      As[(kq * 4 + 0) * 68 + row] = v.x;
      As[(kq * 4 + 1) * 68 + row] = v.y;
      As[(kq * 4 + 2) * 68 + row] = v.z;
      As[(kq * 4 + 3) * 68 + row] = v.w;
    }
    #pragma unroll
    for (int q = 0; q < (32 * COUT) / 1024; ++q) {  // stage B row-major
      int idx = q * 256 + t;
      *(float4*)&Bs[idx * 4] = *(const float4*)&W[k0 * COUT + idx * 4];
    }
    __syncthreads();
    #pragma unroll
    for (int kk = 0; kk < 32; ++kk) {
      float4 av = *(const float4*)&As[kk * 68 + tm * 4];
      float bv[NB];
      if constexpr (COUT == 32) {
        float2 b2 = *(const float2*)&Bs[kk * 32 + tn * 2];
        bv[0] = b2.x; bv[1] = b2.y;
      } else {
        float4 b4 = *(const float4*)&Bs[kk * 64 + tn * 4];
        bv[0] = b4.x; bv[1] = b4.y; bv[2] = b4.z; bv[3] = b4.w;
      }
      const float am[4] = {av.x, av.y, av.z, av.w};
      #pragma unroll
      for (int mi = 0; mi < 4; ++mi)
        #pragma unroll
        for (int nj = 0; nj < NB; ++nj)
          acc[mi][nj] = fmaf(am[mi], bv[nj], acc[mi][nj]);
    }
    __syncthreads();
  }
  // mean (deg) applies only to the aggregated part
  #pragma unroll
  for (int mi = 0; mi < 4; ++mi) {
    int m = c0 + mBase + tm * 4 + mi;
    float rd = 1.f / (float)max(deg[m], 1);
    #pragma unroll
    for (int nj = 0; nj < NB; ++nj) acc[mi][nj] *= rd;
  }
  // root phase: one BK=32 pass with A=X rows, B=root
  {
    #pragma unroll
    for (int q = 0; q < 2; ++q) {
      int idx = q * 256 + t;
      int row = idx >> 3, kq = idx & 7;
      int gr = min(c0 + mBase + row, Nvalid - 1);
      float4 v = *(const float4*)&X[(size_t)gr * 32 + kq * 4];
      As[(kq * 4 + 0) * 68 + row] = v.x;
      As[(kq * 4 + 1) * 68 + row] = v.y;
      As[(kq * 4 + 2) * 68 + row] = v.z;
      As[(kq * 4 + 3) * 68 + row] = v.w;
    }
    #pragma unroll
    for (int q = 0; q < (32 * COUT) / 1024; ++q) {
      int idx = q * 256 + t;
      *(float4*)&Bs[idx * 4] = *(const float4*)&root[idx * 4];
    }
    __syncthreads();
    #pragma unroll
    for (int kk = 0; kk < 32; ++kk) {
      float4 av = *(const float4*)&As[kk * 68 + tm * 4];
      float bv[NB];
      if constexpr (COUT == 32) {
        float2 b2 = *(const float2*)&Bs[kk * 32 + tn * 2];
        bv[0] = b2.x; bv[1] = b2.y;
      } else {
        float4 b4 = *(const float4*)&Bs[kk * 64 + tn * 4];
        bv[0] = b4.x; bv[1] = b4.y; bv[2] = b4.z; bv[3] = b4.w;
      }
      const float am[4] = {av.x, av.y, av.z, av.w};
      #pragma unroll
      for (int mi = 0; mi < 4; ++mi)
        #pragma unroll
        for (int nj = 0; nj < NB; ++nj)
          acc[mi][nj] = fmaf(am[mi], bv[nj], acc[mi][nj]);
    }
  }
  float bv[NB];
  #pragma unroll
  for (int nj = 0; nj < NB; ++nj) bv[nj] = bias[tn * NB + nj];
  #pragma unroll
  for (int mi = 0; mi < 4; ++mi) {
    int m = c0 + mBase + tm * 4 + mi;
    if (m < Nvalid) {
      if constexpr (COUT == 32) {
        float2 o;
        o.x = fmaxf(acc[mi][0] + bv[0], 0.f);
        o.y = fmaxf(acc[mi][1] + bv[1], 0.f);
        *(float2*)&H[(size_t)m * 32 + tn * 2] = o;
      } else {
        float4 o;
        o.x = fmaxf(acc[mi][0] + bv[0], 0.f);
        o.y = fmaxf(acc[mi][1] + bv[1], 0.f);
        o.z = fmaxf(acc[mi][2] + bv[2], 0.f);
        o.w = fmaxf(acc[mi][3] + bv[3], 0.f);
        *(float4*)&H[(size_t)m * 64 + tn * 4] = o;
      }
    }
  }
}

__global__ __launch_bounds__(256) void pool_kernel(
    const float* __restrict__ h2, const int* __restrict__ batch, int N,
    float* __restrict__ poolacc) {
  __shared__ float red[4][64];
  int g = blockIdx.x >> 2, part = blockIdx.x & 3;
  int lo = lowb(batch, N, g), hi = lowb(batch, N, g + 1);
  int len = hi - lo;
  int b0 = lo + (int)(((long long)len * part) / 4);
  int b1 = lo + (int)(((long long)len * (part + 1)) / 4);
  int r = threadIdx.x >> 6, o = threadIdx.x & 63;
  float s = 0.f;
  for (int row = b0 + r; row < b1; row += 4) s += h2[(size_t)row * 64 + o];
  red[r][o] = s;
  __syncthreads();
  if (r == 0) {
    float v = red[0][o] + red[1][o] + red[2][o] + red[3][o];
    atomicAdd(&poolacc[g * 64 + o], v);
  }
}

__global__ __launch_bounds__(64) void head_kernel(
    const float* __restrict__ poolacc, const int* __restrict__ batch, int N,
    const float* __restrict__ w1, const float* __restrict__ b1,
    const float* __restrict__ w2, const float* __restrict__ b2,
    const float* __restrict__ w3, const float* __restrict__ b3,
    float* __restrict__ out) {
  __shared__ float gb[64];
  __shared__ float lg[10];
  int g = blockIdx.x, o = threadIdx.x;
  int lo = lowb(batch, N, g), hi = lowb(batch, N, g + 1);
  float cnt = fmaxf((float)(hi - lo), 1.f);
  float gv = poolacc[g * 64 + o] / cnt;
  gb[o] = gv;
  __syncthreads();
  float tacc = b1[o];
  for (int i = 0; i < 64; ++i) tacc = fmaf(gb[i], w1[i * 64 + o], tacc);
  gv = gv * (1.f / (1.f + expf(-tacc)));
  __syncthreads(); gb[o] = gv; __syncthreads();
  tacc = b2[o];
  for (int i = 0; i < 64; ++i) tacc = fmaf(gb[i], w2[i * 64 + o], tacc);
  gv = gv * (1.f / (1.f + expf(-tacc)));
  __syncthreads(); gb[o] = gv; __syncthreads();
  if (o < 10) {
    float l = b3[o];
    for (int i = 0; i < 64; ++i) l = fmaf(gb[i], w3[i * 10 + o], l);
    lg[o] = l;
  }
  __syncthreads();
  if (o < 10) {
    float m = lg[0];
    #pragma unroll
    for (int c = 1; c < 10; ++c) m = fmaxf(m, lg[c]);
    float s = 0.f;
    #pragma unroll
    for (int c = 0; c < 10; ++c) s += expf(lg[c] - m);
    out[g * 10 + o] = lg[o] - m - logf(s);
  }
}

extern "C" void kernel_launch(void* const* d_in, const int* in_sizes, int n_in,
                              void* d_out, int out_size, void* d_ws, size_t ws_size,
                              hipStream_t stream) {
  const float* x     = (const float*)d_in[0];
  const int*   ei    = (const int*)d_in[1];
  const float* eattr = (const float*)d_in[2];
  const int*   batch = (const int*)d_in[3];
  const float* W1    = (const float*)d_in[4];
  const float* root1 = (const float*)d_in[5];
  const float* b1    = (const float*)d_in[6];
  const float* W2    = (const float*)d_in[7];
  const float* root2 = (const float*)d_in[8];
  const float* b2    = (const float*)d_in[9];
  const float* l1w   = (const float*)d_in[10];
  const float* l1b   = (const float*)d_in[11];
  const float* l2w   = (const float*)d_in[12];
  const float* l2b   = (const float*)d_in[13];
  const float* l3w   = (const float*)d_in[14];
  const float* l3b   = (const float*)d_in[15];
  float* out = (float*)d_out;

  const int N = in_sizes[0] / 32;
  const int E = in_sizes[1] / 2;
  const int Npad = (N + 63) & ~63;

  char* base = (char*)d_ws;
  size_t off = 0;
  auto walloc = [&](size_t bytes) -> void* {
    off = (off + 255) & ~(size_t)255;
    void* p = base + off;
    off += bytes;
    return p;
  };
  int*   deg     = (int*)walloc((size_t)Npad * 4);
  int*   offs    = (int*)walloc((size_t)(N + 1) * 4);
  int*   cursor  = (int*)walloc((size_t)N * 4);
  int*   bsums   = (int*)walloc(64 * 4);
  int*   boff    = (int*)walloc(64 * 4);
  float* poolacc = (float*)walloc(64 * 64 * 4);
  float* h1      = (float*)walloc((size_t)N * 32 * 4);
  float* h2      = (float*)walloc((size_t)N * 64 * 4);
  int2*  recs    = (int2*)walloc((size_t)E * 8);
  off = (off + 255) & ~(size_t)255;
  size_t remain = (ws_size > off) ? (ws_size - off) : 0;
  int chunkRows = (int)(remain / (800 * 4));
  chunkRows &= ~63;
  if (chunkRows > 12800) chunkRows = 12800;
  if (chunkRows > Npad) chunkRows = Npad;
  if (chunkRows < 64) return;               // insufficient workspace
  float* T = (float*)(base + off);

  const int* srcA = ei;
  const int* dstA = ei + E;

  hipMemsetAsync(deg, 0, (size_t)Npad * 4, stream);
  hipMemsetAsync(cursor, 0, (size_t)N * 4, stream);
  hipMemsetAsync(poolacc, 0, 64 * 64 * 4, stream);

  hist_kernel<<<(E + 255) / 256, 256, 0, stream>>>(dstA, E, deg);
  int nb = (N + 1023) / 1024;
  scan_block_kernel<<<nb, 1024, 0, stream>>>(deg, N, offs, bsums);
  scan_bsums_kernel<<<1, 64, 0, stream>>>(bsums, nb, boff);
  scan_add_kernel<<<(N + 255) / 256, 256, 0, stream>>>(offs, boff, N);
  scatter_kernel<<<(E + 255) / 256, 256, 0, stream>>>(srcA, dstA, E, offs, cursor, recs);

  for (int layer = 0; layer < 2; ++layer) {
    const float* Xin = layer ? h1 : x;
    const float* Wl  = layer ? W2 : W1;
    const float* rl  = layer ? root2 : root1;
    const float* bl  = layer ? b2 : b1;
    float* Hout      = layer ? h2 : h1;
    for (int c0 = 0; c0 < N; c0 += chunkRows) {
      int cn = (chunkRows < N - c0) ? chunkRows : (N - c0);
      int accBlocks = (cn + 7) / 8;
      acc_kernel<<<accBlocks, 512, 0, stream>>>(recs, offs, (const float2*)eattr,
                                                Xin, T, c0, c0 + cn);
      int tiles = (cn + 63) / 64;
      if (layer == 0)
        gemm_kernel<32><<<tiles, 256, 0, stream>>>(T, Wl, Xin, rl, bl, deg, Hout, c0, N);
      else
        gemm_kernel<64><<<tiles, 256, 0, stream>>>(T, Wl, Xin, rl, bl, deg, Hout, c0, N);
    }
  }
  pool_kernel<<<256, 256, 0, stream>>>(h2, batch, N, poolacc);
  head_kernel<<<64, 64, 0, stream>>>(poolacc, batch, N,
                                     l1w, l1b, l2w, l2b, l3w, l3b, out);
}

// Round 4
// 995.313 us; speedup vs baseline: 3.2860x; 2.8944x over previous
//
#include <hip/hip_runtime.h>
#include <hip/hip_bf16.h>
#include <cstdint>

// ---------------------------------------------------------------------------
// SplineNet forward on gfx950 — gather formulation (no scatter, no atomics in
// the conv path):
//   Y[n, k*Cout+ch] = x[n] @ W[k]            (dense GEMM, coalesced)
//   agg[n, ch]      = sum_e sum_s basis_s(e) * Y[src_e, kidx_s, ch]
//                     (wave-per-node over CSR, lane=channel, register acc)
//   h[n]            = relu(agg/deg + x[n]@root + b)   (finalize)
// Y is chunked over the i1 spline dimension into G-groups to fit ws_size;
// bf16 Y fallback if fp32 G=1 does not fit.
// ---------------------------------------------------------------------------

__device__ __forceinline__ float ldy(const float* p) { return *p; }
__device__ __forceinline__ float ldy(const __hip_bfloat16* p) { return __bfloat162float(*p); }
__device__ __forceinline__ void sty(float* p, float v) { *p = v; }
__device__ __forceinline__ void sty(__hip_bfloat16* p, float v) { *p = __float2bfloat16(v); }

__device__ __forceinline__ int lowb(const int* __restrict__ a, int n, int v) {
  int lo = 0, hi = n;
  while (lo < hi) { int m = (lo + hi) >> 1; if (a[m] < v) lo = m + 1; else hi = m; }
  return lo;
}

__global__ void hist_kernel(const int* __restrict__ dst, int E, int* __restrict__ deg) {
  int e = blockIdx.x * 256 + threadIdx.x;
  if (e < E) atomicAdd(&deg[dst[e]], 1);
}

__global__ __launch_bounds__(1024) void scan_block_kernel(
    const int* __restrict__ deg, int n, int* __restrict__ offs, int* __restrict__ bsums) {
  __shared__ int wsum[16];
  int t = threadIdx.x;
  int gi = blockIdx.x * 1024 + t;
  int v = (gi < n) ? deg[gi] : 0;
  int lane = t & 63, w = t >> 6;
  int x = v;
  #pragma unroll
  for (int d = 1; d < 64; d <<= 1) { int y = __shfl_up(x, d, 64); if (lane >= d) x += y; }
  if (lane == 63) wsum[w] = x;
  __syncthreads();
  if (w == 0) {
    int s = (lane < 16) ? wsum[lane] : 0;
    #pragma unroll
    for (int d = 1; d < 16; d <<= 1) { int y = __shfl_up(s, d, 64); if (lane >= d) s += y; }
    if (lane < 16) wsum[lane] = s;
  }
  __syncthreads();
  int add = (w > 0) ? wsum[w - 1] : 0;
  x += add;
  if (gi < n) offs[gi + 1] = x;
  if (t == 1023) bsums[blockIdx.x] = x;
}

__global__ __launch_bounds__(64) void scan_bsums_kernel(
    const int* __restrict__ bsums, int nb, int* __restrict__ boff) {
  int l = threadIdx.x;
  int v = (l < nb) ? bsums[l] : 0;
  int x = v;
  #pragma unroll
  for (int d = 1; d < 64; d <<= 1) { int y = __shfl_up(x, d, 64); if (l >= d) x += y; }
  if (l < nb) boff[l] = x - v;
}

__global__ void scan_add_kernel(int* __restrict__ offs, const int* __restrict__ boff, int n) {
  int i = blockIdx.x * 256 + threadIdx.x;
  if (i < n) offs[i + 1] += boff[i >> 10];
  if (i == 0) offs[0] = 0;
}

__global__ void scatter_kernel(const int* __restrict__ src, const int* __restrict__ dst, int E,
                               const int* __restrict__ offs, int* __restrict__ cursor,
                               int2* __restrict__ recs) {
  int e = blockIdx.x * 256 + threadIdx.x;
  if (e < E) {
    int d = dst[e];
    int p = offs[d] + atomicAdd(&cursor[d], 1);
    recs[p] = make_int2(src[e], e);
  }
}

// Y[n, kk*COUT+ch] = sum_i X[n,i] * Wsrc[kFirst+kk][i][ch], kk in [0,kCount)
template <int COUT, typename YT>
__global__ __launch_bounds__(256) void ygemm_kernel(
    const float* __restrict__ X, const float* __restrict__ Wsrc,
    YT* __restrict__ Y, int N, int kFirst, int kCount, int strideY) {
  __shared__ float Xs[64][33];
  __shared__ float Ws[32 * COUT];
  const int t = threadIdx.x;
  const int n0 = blockIdx.x * 64;
  {
    int row = t >> 2, c8 = (t & 3) << 3;
    const float* xr = X + (size_t)min(n0 + row, N - 1) * 32 + c8;
    float4 va = *(const float4*)xr;
    float4 vb = *(const float4*)(xr + 4);
    Xs[row][c8 + 0] = va.x; Xs[row][c8 + 1] = va.y;
    Xs[row][c8 + 2] = va.z; Xs[row][c8 + 3] = va.w;
    Xs[row][c8 + 4] = vb.x; Xs[row][c8 + 5] = vb.y;
    Xs[row][c8 + 6] = vb.z; Xs[row][c8 + 7] = vb.w;
  }
  const int w = t >> 6, lane = t & 63;
  const int row = w * 16 + (lane >> 2);
  constexpr int CW = COUT / 4;
  const int c0 = (lane & 3) * CW;
  const int gRow = n0 + row;
  for (int kk = 0; kk < kCount; ++kk) {
    __syncthreads();
    {
      const float* wp = Wsrc + (size_t)(kFirst + kk) * 32 * COUT;
      constexpr int PF = (32 * COUT) / 256;   // floats per thread (4 or 8)
      #pragma unroll
      for (int q = 0; q < PF / 4; ++q)
        *(float4*)&Ws[t * PF + q * 4] = *(const float4*)&wp[t * PF + q * 4];
    }
    __syncthreads();
    float acc[CW];
    #pragma unroll
    for (int j = 0; j < CW; ++j) acc[j] = 0.f;
    #pragma unroll
    for (int i = 0; i < 32; ++i) {
      float xv = Xs[row][i];
      const float* wr = &Ws[i * COUT + c0];
      #pragma unroll
      for (int j = 0; j < CW; ++j) acc[j] = fmaf(xv, wr[j], acc[j]);
    }
    if (gRow < N) {
      YT* yp = Y + (size_t)gRow * (size_t)strideY + kk * COUT + c0;
      #pragma unroll
      for (int j = 0; j < CW; ++j) sty(yp + j, acc[j]);
    }
  }
}

// Wave-per-node gather: agg[n,ch] += sum_e sum_s basis * Y[src, k_s, ch]
// Phase A: lane-parallel edge metadata; Phase B: shfl-broadcast + coalesced
// Y-row loads, register accumulation. i1 group restricted to [g0, g1).
template <int COUT, typename YT>
__global__ __launch_bounds__(256) void gather_kernel(
    const int2* __restrict__ recs, const int* __restrict__ offs,
    const float2* __restrict__ attr, const YT* __restrict__ Y, int strideY,
    float* __restrict__ hagg, int N, int g0, int g1, int first) {
  const int w = threadIdx.x >> 6, lane = threadIdx.x & 63;
  const int n = blockIdx.x * 4 + w;
  if (n >= N) return;
  const int ch = (COUT == 32) ? (lane & 31) : lane;
  const int h = (COUT == 32) ? (lane >> 5) : 0;
  const int beg = offs[n], end = offs[n + 1];
  float acc = 0.f;
  for (int b0 = beg; b0 < end; b0 += 64) {
    const int cnt = min(64, end - b0);
    int el = b0 + min(lane, cnt - 1);
    int2 r = recs[el];
    float2 a = attr[r.y];
    float v0 = a.x * 4.f, v1 = a.y * 4.f;
    float fl0 = floorf(v0), fl1 = floorf(v1);
    float f0 = v0 - fl0, f1 = v1 - fl1;
    int i00 = min((int)fl0, 4);
    int i10 = min((int)fl1, 4);
    int i11 = min(i10 + 1, 4);
    bool in0 = (i10 >= g0) && (i10 < g1);
    bool in1 = (i11 >= g0) && (i11 < g1);
    int kb0 = in0 ? ((i10 - g0) * 5 + i00) : 0;
    int kb1 = in1 ? ((i11 - g0) * 5 + i00) : 0;
    float wA = in0 ? (1.f - f0) * (1.f - f1) : 0.f;
    float wB = in0 ? f0 * (1.f - f1) : 0.f;
    float wC = in1 ? (1.f - f0) * f1 : 0.f;
    float wD = in1 ? f0 * f1 : 0.f;
    int mySrc = r.x;
    const int EPW = (COUT == 32) ? 2 : 1;   // edges per wave step
    const int steps = (cnt + EPW - 1) / EPW;
    #pragma unroll 2
    for (int j = 0; j < steps; ++j) {
      int je = j * EPW + h;
      int jc = (je < cnt) ? je : 0;
      int srcS = __shfl(mySrc, jc);
      int k0 = __shfl(kb0, jc);
      int k1 = __shfl(kb1, jc);
      float a0 = __shfl(wA, jc);
      float a1 = __shfl(wB, jc);
      float a2 = __shfl(wC, jc);
      float a3 = __shfl(wD, jc);
      if (je >= cnt) { a0 = 0.f; a1 = 0.f; a2 = 0.f; a3 = 0.f; }
      const YT* yr = Y + (size_t)srcS * (size_t)strideY;
      float y0 = ldy(yr + k0 * COUT + ch);
      float y1 = ldy(yr + k0 * COUT + COUT + ch);
      float y2 = ldy(yr + k1 * COUT + ch);
      float y3 = ldy(yr + k1 * COUT + COUT + ch);
      acc += a0 * y0 + a1 * y1 + a2 * y2 + a3 * y3;
    }
  }
  if (COUT == 32) acc += __shfl_xor(acc, 32);
  if (lane < COUT) {
    float* hp = hagg + (size_t)n * COUT + ch;
    if (first) *hp = acc; else *hp += acc;
  }
}

// h[n,ch] = relu(agg[n,ch]/max(deg,1) + x[n]@root[:,ch] + b[ch]); in-place ok.
template <int COUT>
__global__ __launch_bounds__(256) void finalize_kernel(
    const float* __restrict__ hagg, const float* __restrict__ X,
    const float* __restrict__ root, const float* __restrict__ bias,
    const int* __restrict__ deg, float* __restrict__ hout, int N) {
  __shared__ float Rs[32 * COUT];
  int t = threadIdx.x;
  #pragma unroll
  for (int q = 0; q < (32 * COUT) / 1024; ++q)
    *(float4*)&Rs[(q * 256 + t) * 4] = *(const float4*)&root[(q * 256 + t) * 4];
  __syncthreads();
  constexpr int TPN = COUT / 4;
  int gid = blockIdx.x * 256 + t;
  int n = gid / TPN;
  int c0 = (gid % TPN) * 4;
  if (n >= N) return;
  const float* xr = X + (size_t)n * 32;
  float rd = 1.f / (float)max(deg[n], 1);
  float4 hv = *(const float4*)&hagg[(size_t)n * COUT + c0];
  float a0 = hv.x * rd, a1 = hv.y * rd, a2 = hv.z * rd, a3 = hv.w * rd;
  #pragma unroll
  for (int i = 0; i < 32; ++i) {
    float xv = xr[i];
    const float* rr = &Rs[i * COUT + c0];
    a0 = fmaf(xv, rr[0], a0);
    a1 = fmaf(xv, rr[1], a1);
    a2 = fmaf(xv, rr[2], a2);
    a3 = fmaf(xv, rr[3], a3);
  }
  float4 o;
  o.x = fmaxf(a0 + bias[c0 + 0], 0.f);
  o.y = fmaxf(a1 + bias[c0 + 1], 0.f);
  o.z = fmaxf(a2 + bias[c0 + 2], 0.f);
  o.w = fmaxf(a3 + bias[c0 + 3], 0.f);
  *(float4*)&hout[(size_t)n * COUT + c0] = o;
}

__global__ __launch_bounds__(256) void pool_kernel(
    const float* __restrict__ h2, const int* __restrict__ batch, int N,
    float* __restrict__ poolacc) {
  __shared__ float red[4][64];
  int g = blockIdx.x >> 2, part = blockIdx.x & 3;
  int lo = lowb(batch, N, g), hi = lowb(batch, N, g + 1);
  int len = hi - lo;
  int b0 = lo + (int)(((long long)len * part) / 4);
  int b1 = lo + (int)(((long long)len * (part + 1)) / 4);
  int r = threadIdx.x >> 6, o = threadIdx.x & 63;
  float s = 0.f;
  for (int row = b0 + r; row < b1; row += 4) s += h2[(size_t)row * 64 + o];
  red[r][o] = s;
  __syncthreads();
  if (r == 0) {
    float v = red[0][o] + red[1][o] + red[2][o] + red[3][o];
    atomicAdd(&poolacc[g * 64 + o], v);
  }
}

__global__ __launch_bounds__(64) void head_kernel(
    const float* __restrict__ poolacc, const int* __restrict__ batch, int N,
    const float* __restrict__ w1, const float* __restrict__ b1,
    const float* __restrict__ w2, const float* __restrict__ b2,
    const float* __restrict__ w3, const float* __restrict__ b3,
    float* __restrict__ out) {
  __shared__ float gb[64];
  __shared__ float lg[10];
  int g = blockIdx.x, o = threadIdx.x;
  int lo = lowb(batch, N, g), hi = lowb(batch, N, g + 1);
  float cnt = fmaxf((float)(hi - lo), 1.f);
  float gv = poolacc[g * 64 + o] / cnt;
  gb[o] = gv;
  __syncthreads();
  float tacc = b1[o];
  for (int i = 0; i < 64; ++i) tacc = fmaf(gb[i], w1[i * 64 + o], tacc);
  gv = gv * (1.f / (1.f + expf(-tacc)));
  __syncthreads(); gb[o] = gv; __syncthreads();
  tacc = b2[o];
  for (int i = 0; i < 64; ++i) tacc = fmaf(gb[i], w2[i * 64 + o], tacc);
  gv = gv * (1.f / (1.f + expf(-tacc)));
  __syncthreads(); gb[o] = gv; __syncthreads();
  if (o < 10) {
    float l = b3[o];
    for (int i = 0; i < 64; ++i) l = fmaf(gb[i], w3[i * 10 + o], l);
    lg[o] = l;
  }
  __syncthreads();
  if (o < 10) {
    float m = lg[0];
    #pragma unroll
    for (int c = 1; c < 10; ++c) m = fmaxf(m, lg[c]);
    float s = 0.f;
    #pragma unroll
    for (int c = 0; c < 10; ++c) s += expf(lg[c] - m);
    out[g * 10 + o] = lg[o] - m - logf(s);
  }
}

extern "C" void kernel_launch(void* const* d_in, const int* in_sizes, int n_in,
                              void* d_out, int out_size, void* d_ws, size_t ws_size,
                              hipStream_t stream) {
  const float* x     = (const float*)d_in[0];
  const int*   ei    = (const int*)d_in[1];
  const float* eattr = (const float*)d_in[2];
  const int*   batch = (const int*)d_in[3];
  const float* W1    = (const float*)d_in[4];
  const float* root1 = (const float*)d_in[5];
  const float* b1    = (const float*)d_in[6];
  const float* W2    = (const float*)d_in[7];
  const float* root2 = (const float*)d_in[8];
  const float* b2    = (const float*)d_in[9];
  const float* l1w   = (const float*)d_in[10];
  const float* l1b   = (const float*)d_in[11];
  const float* l2w   = (const float*)d_in[12];
  const float* l2b   = (const float*)d_in[13];
  const float* l3w   = (const float*)d_in[14];
  const float* l3b   = (const float*)d_in[15];
  float* out = (float*)d_out;

  const int N = in_sizes[0] / 32;
  const int E = in_sizes[1] / 2;
  const int Npad = (N + 63) & ~63;

  char* base = (char*)d_ws;
  size_t off = 0;
  auto walloc = [&](size_t bytes) -> void* {
    off = (off + 255) & ~(size_t)255;
    void* p = base + off;
    off += bytes;
    return p;
  };
  int*   deg     = (int*)walloc((size_t)Npad * 4);
  int*   offs    = (int*)walloc((size_t)(N + 1) * 4);
  int*   cursor  = (int*)walloc((size_t)N * 4);
  int*   bsums   = (int*)walloc(64 * 4);
  int*   boff    = (int*)walloc(64 * 4);
  float* poolacc = (float*)walloc(64 * 64 * 4);
  float* h1      = (float*)walloc((size_t)N * 32 * 4);
  float* h2      = (float*)walloc((size_t)N * 64 * 4);
  int2*  recs    = (int2*)walloc((size_t)E * 8);
  off = (off + 255) & ~(size_t)255;
  size_t yAvail = (ws_size > off + 2048) ? (ws_size - off - 2048) : 0;
  void* Yb = (void*)(base + off);

  // pick i1-group width G (1..5) for a given Cout and element size
  auto pickG = [&](int cout, size_t elem) -> int {
    size_t per5 = (size_t)N * 5 * cout * elem;   // bytes per i1 group
    if (per5 == 0 || yAvail < per5) return 0;
    size_t g = yAvail / per5;
    return (int)(g > 5 ? 5 : g);
  };
  bool bf1 = false, bf2 = false;
  int G1 = pickG(32, 4); if (!G1) { G1 = pickG(32, 2); bf1 = true; }
  int G2 = pickG(64, 4); if (!G2) { G2 = pickG(64, 2); bf2 = true; }
  if (!G1 || !G2) return;   // insufficient workspace

  const int* srcA = ei;
  const int* dstA = ei + E;

  hipMemsetAsync(deg, 0, (size_t)Npad * 4, stream);
  hipMemsetAsync(cursor, 0, (size_t)N * 4, stream);
  hipMemsetAsync(poolacc, 0, 64 * 64 * 4, stream);

  hist_kernel<<<(E + 255) / 256, 256, 0, stream>>>(dstA, E, deg);
  int nb = (N + 1023) / 1024;
  scan_block_kernel<<<nb, 1024, 0, stream>>>(deg, N, offs, bsums);
  scan_bsums_kernel<<<1, 64, 0, stream>>>(bsums, nb, boff);
  scan_add_kernel<<<(N + 255) / 256, 256, 0, stream>>>(offs, boff, N);
  scatter_kernel<<<(E + 255) / 256, 256, 0, stream>>>(srcA, dstA, E, offs, cursor, recs);

  const int ygrid = (N + 63) / 64;
  const int ggrid = (N + 3) / 4;
  for (int layer = 0; layer < 2; ++layer) {
    const float* Xin = layer ? h1 : x;
    const float* Wl  = layer ? W2 : W1;
    const float* rl  = layer ? root2 : root1;
    const float* bl  = layer ? b2 : b1;
    float* Hout      = layer ? h2 : h1;
    const int G      = layer ? G2 : G1;
    const bool bf    = layer ? bf2 : bf1;
    for (int g0 = 0, p = 0; g0 < 5; g0 += G, ++p) {
      int g1 = min(5, g0 + G);
      int kFirst = g0 * 5, kCount = (g1 - g0) * 5;
      int strideY = 0;
      strideY = kCount * (layer ? 64 : 32);
      int first = (p == 0) ? 1 : 0;
      if (layer == 0) {
        if (!bf) {
          ygemm_kernel<32, float><<<ygrid, 256, 0, stream>>>(
              Xin, Wl, (float*)Yb, N, kFirst, kCount, strideY);
          gather_kernel<32, float><<<ggrid, 256, 0, stream>>>(
              recs, offs, (const float2*)eattr, (const float*)Yb, strideY,
              Hout, N, g0, g1, first);
        } else {
          ygemm_kernel<32, __hip_bfloat16><<<ygrid, 256, 0, stream>>>(
              Xin, Wl, (__hip_bfloat16*)Yb, N, kFirst, kCount, strideY);
          gather_kernel<32, __hip_bfloat16><<<ggrid, 256, 0, stream>>>(
              recs, offs, (const float2*)eattr, (const __hip_bfloat16*)Yb, strideY,
              Hout, N, g0, g1, first);
        }
      } else {
        if (!bf) {
          ygemm_kernel<64, float><<<ygrid, 256, 0, stream>>>(
              Xin, Wl, (float*)Yb, N, kFirst, kCount, strideY);
          gather_kernel<64, float><<<ggrid, 256, 0, stream>>>(
              recs, offs, (const float2*)eattr, (const float*)Yb, strideY,
              Hout, N, g0, g1, first);
        } else {
          ygemm_kernel<64, __hip_bfloat16><<<ygrid, 256, 0, stream>>>(
              Xin, Wl, (__hip_bfloat16*)Yb, N, kFirst, kCount, strideY);
          gather_kernel<64, __hip_bfloat16><<<ggrid, 256, 0, stream>>>(
              recs, offs, (const float2*)eattr, (const __hip_bfloat16*)Yb, strideY,
              Hout, N, g0, g1, first);
        }
      }
    }
    if (layer == 0)
      finalize_kernel<32><<<((size_t)N * 8 + 255) / 256, 256, 0, stream>>>(
          Hout, Xin, rl, bl, deg, Hout, N);
    else
      finalize_kernel<64><<<((size_t)N * 16 + 255) / 256, 256, 0, stream>>>(
          Hout, Xin, rl, bl, deg, Hout, N);
  }
  pool_kernel<<<256, 256, 0, stream>>>(h2, batch, N, poolacc);
  head_kernel<<<64, 64, 0, stream>>>(poolacc, batch, N,
                                     l1w, l1b, l2w, l2b, l3w, l3b, out);
}

// Round 5
// 665.347 us; speedup vs baseline: 4.9157x; 1.4959x over previous
//
#include <hip/hip_runtime.h>
#include <hip/hip_bf16.h>
#include <hip/hip_fp16.h>
#include <cstdint>

// ---------------------------------------------------------------------------
// SplineNet forward on gfx950 — gather formulation, fp16 Y, packed edge meta.
//   Y[n, k*Cout+ch] = x[n] @ W[k]                     (ygemm, fp16 out)
//   agg[n, ch]      = sum_e sum_s basis_s(e) * Y[src_e, k_s, ch]
//     wave-per-node; lane quarter q owns spline slot (q&1, q>>1); 16 lanes
//     per quarter cover channels (half2/8B loads) -> ONE vector load per edge;
//     cross-quarter reduction deferred to after the edge loop.
//   h[n] = relu(agg/deg + x[n]@root + b)              (finalize)
// Edge meta {src, k0|i10<<8, f0, f1} precomputed in scatter (coalesced attr).
// L1 Y chunked over i1 groups to fit ws; out-of-group edges skip (uniform br).
// ---------------------------------------------------------------------------

struct H4 { __half2 a, b; };

__device__ __forceinline__ int lowb(const int* __restrict__ a, int n, int v) {
  int lo = 0, hi = n;
  while (lo < hi) { int m = (lo + hi) >> 1; if (a[m] < v) lo = m + 1; else hi = m; }
  return lo;
}

__global__ void hist_kernel(const int* __restrict__ dst, int E, int* __restrict__ deg) {
  int e = blockIdx.x * 256 + threadIdx.x;
  if (e < E) atomicAdd(&deg[dst[e]], 1);
}

__global__ __launch_bounds__(1024) void scan_block_kernel(
    const int* __restrict__ deg, int n, int* __restrict__ offs, int* __restrict__ bsums) {
  __shared__ int wsum[16];
  int t = threadIdx.x;
  int gi = blockIdx.x * 1024 + t;
  int v = (gi < n) ? deg[gi] : 0;
  int lane = t & 63, w = t >> 6;
  int x = v;
  #pragma unroll
  for (int d = 1; d < 64; d <<= 1) { int y = __shfl_up(x, d, 64); if (lane >= d) x += y; }
  if (lane == 63) wsum[w] = x;
  __syncthreads();
  if (w == 0) {
    int s = (lane < 16) ? wsum[lane] : 0;
    #pragma unroll
    for (int d = 1; d < 16; d <<= 1) { int y = __shfl_up(s, d, 64); if (lane >= d) s += y; }
    if (lane < 16) wsum[lane] = s;
  }
  __syncthreads();
  int add = (w > 0) ? wsum[w - 1] : 0;
  x += add;
  if (gi < n) offs[gi + 1] = x;
  if (t == 1023) bsums[blockIdx.x] = x;
}

__global__ __launch_bounds__(64) void scan_bsums_kernel(
    const int* __restrict__ bsums, int nb, int* __restrict__ boff) {
  int l = threadIdx.x;
  int v = (l < nb) ? bsums[l] : 0;
  int x = v;
  #pragma unroll
  for (int d = 1; d < 64; d <<= 1) { int y = __shfl_up(x, d, 64); if (l >= d) x += y; }
  if (l < nb) boff[l] = x - v;
}

__global__ void scan_add_kernel(int* __restrict__ offs, const int* __restrict__ boff, int n) {
  int i = blockIdx.x * 256 + threadIdx.x;
  if (i < n) offs[i + 1] += boff[i >> 10];
  if (i == 0) offs[0] = 0;
}

// CSR scatter + spline metadata precompute (attr read coalesced here, once).
__global__ void scatter_kernel(const int* __restrict__ src, const int* __restrict__ dst,
                               const float2* __restrict__ attr, int E,
                               const int* __restrict__ offs, int* __restrict__ cursor,
                               int4* __restrict__ emeta) {
  int e = blockIdx.x * 256 + threadIdx.x;
  if (e < E) {
    float2 a = attr[e];
    float v0 = a.x * 4.f, v1 = a.y * 4.f;
    int i00 = min((int)floorf(v0), 3);
    int i10 = min((int)floorf(v1), 3);
    float f0 = v0 - (float)i00;             // clamp trick: i in [0,3], f in [0,1]
    float f1 = v1 - (float)i10;             // (boundary cases exact, no branches)
    int k0 = i10 * 5 + i00;
    int d = dst[e];
    int p = offs[d] + atomicAdd(&cursor[d], 1);
    emeta[p] = make_int4(src[e], k0 | (i10 << 8),
                         __float_as_int(f0), __float_as_int(f1));
  }
}

// Y[n, kk*COUT+ch] = sum_i X[n,i] * Wsrc[kFirst+kk][i][ch], fp16 out.
template <int COUT>
__global__ __launch_bounds__(256) void ygemm_kernel(
    const float* __restrict__ X, const float* __restrict__ Wsrc,
    __half* __restrict__ Y, int N, int kFirst, int kCount, int strideY) {
  __shared__ float Xs[64][33];
  __shared__ float Ws[32 * COUT];
  const int t = threadIdx.x;
  const int n0 = blockIdx.x * 64;
  {
    int row = t >> 2, c8 = (t & 3) << 3;
    const float* xr = X + (size_t)min(n0 + row, N - 1) * 32 + c8;
    float4 va = *(const float4*)xr;
    float4 vb = *(const float4*)(xr + 4);
    Xs[row][c8 + 0] = va.x; Xs[row][c8 + 1] = va.y;
    Xs[row][c8 + 2] = va.z; Xs[row][c8 + 3] = va.w;
    Xs[row][c8 + 4] = vb.x; Xs[row][c8 + 5] = vb.y;
    Xs[row][c8 + 6] = vb.z; Xs[row][c8 + 7] = vb.w;
  }
  const int w = t >> 6, lane = t & 63;
  const int row = w * 16 + (lane >> 2);
  constexpr int CW = COUT / 4;
  const int c0 = (lane & 3) * CW;
  const int gRow = n0 + row;
  for (int kk = 0; kk < kCount; ++kk) {
    __syncthreads();
    {
      const float* wp = Wsrc + (size_t)(kFirst + kk) * 32 * COUT;
      constexpr int PF = (32 * COUT) / 256;
      #pragma unroll
      for (int q = 0; q < PF / 4; ++q)
        *(float4*)&Ws[t * PF + q * 4] = *(const float4*)&wp[t * PF + q * 4];
    }
    __syncthreads();
    float acc[CW];
    #pragma unroll
    for (int j = 0; j < CW; ++j) acc[j] = 0.f;
    #pragma unroll
    for (int i = 0; i < 32; ++i) {
      float xv = Xs[row][i];
      const float* wr = &Ws[i * COUT + c0];
      #pragma unroll
      for (int j = 0; j < CW; ++j) acc[j] = fmaf(xv, wr[j], acc[j]);
    }
    if (gRow < N) {
      __half* yp = Y + (size_t)gRow * (size_t)strideY + kk * COUT + c0;
      #pragma unroll
      for (int j = 0; j < CW; j += 2)
        *(__half2*)(yp + j) = __floats2half2_rn(acc[j], acc[j + 1]);
    }
  }
}

// Wave-per-node gather. Lane quarter q = slot (di0=q&1, di1=q>>1); 16 lanes per
// quarter cover channels. One vector load per edge; quarter-sum deferred.
// i1-group [g0,g1): edges outside skip via wave-uniform branch.
template <int COUT>
__global__ __launch_bounds__(256) void gather_kernel(
    const int4* __restrict__ emeta, const int* __restrict__ offs,
    const __half* __restrict__ Y, int strideY,
    float* __restrict__ hagg, int N, int g0, int g1, int first) {
  const int w = threadIdx.x >> 6, lane = threadIdx.x & 63;
  const int n = blockIdx.x * 4 + w;
  if (n >= N) return;
  const int q = lane >> 4, r = lane & 15;
  const int di0 = q & 1, di1 = q >> 1;
  constexpr int CPL = COUT / 16;            // channels per lane: 2 or 4
  const int kBias = di0 + 5 * di1 - 5 * g0; // local row offset for this quarter
  const int laneCh = r * CPL;
  float acc[CPL];
  #pragma unroll
  for (int j = 0; j < CPL; ++j) acc[j] = 0.f;
  const int beg = offs[n], end = offs[n + 1];
  for (int b0 = beg; b0 < end; b0 += 64) {
    const int cnt = min(64, end - b0);
    int4 m = emeta[b0 + min(lane, cnt - 1)];
    int myS = m.x, myK = m.y;
    float myF0 = __int_as_float(m.z), myF1 = __int_as_float(m.w);
    for (int j = 0; j < cnt; ++j) {
      int kw = __shfl(myK, j);
      int i10 = kw >> 8;
      if (i10 < g0 || i10 >= g1) continue;  // wave-uniform skip
      int s = __shfl(myS, j);
      float f0 = __shfl(myF0, j);
      float f1 = __shfl(myF1, j);
      float wgt = (di0 ? f0 : 1.f - f0) * (di1 ? f1 : 1.f - f1);
      int rowL = (kw & 0xff) + kBias;
      const __half* yp = Y + (size_t)s * (size_t)strideY + rowL * COUT + laneCh;
      if (CPL == 2) {
        float2 f = __half22float2(*(const __half2*)yp);
        acc[0] = fmaf(wgt, f.x, acc[0]);
        acc[1] = fmaf(wgt, f.y, acc[1]);
      } else {
        H4 hv = *(const H4*)yp;
        float2 fa = __half22float2(hv.a), fb = __half22float2(hv.b);
        acc[0] = fmaf(wgt, fa.x, acc[0]);
        acc[1] = fmaf(wgt, fa.y, acc[1]);
        acc[2] = fmaf(wgt, fb.x, acc[2]);
        acc[3] = fmaf(wgt, fb.y, acc[3]);
      }
    }
  }
  #pragma unroll
  for (int j = 0; j < CPL; ++j) {           // fold the 4 slot-quarters
    acc[j] += __shfl_xor(acc[j], 16);
    acc[j] += __shfl_xor(acc[j], 32);
  }
  if (lane < 16) {
    float* hp = hagg + (size_t)n * COUT + laneCh;
    if (CPL == 2) {
      float2 o = make_float2(acc[0], acc[1]);
      if (!first) { float2 p = *(float2*)hp; o.x += p.x; o.y += p.y; }
      *(float2*)hp = o;
    } else {
      float4 o = make_float4(acc[0], acc[1], acc[2], acc[3]);
      if (!first) {
        float4 p = *(float4*)hp;
        o.x += p.x; o.y += p.y; o.z += p.z; o.w += p.w;
      }
      *(float4*)hp = o;
    }
  }
}

// h[n,ch] = relu(agg[n,ch]/max(deg,1) + x[n]@root[:,ch] + b[ch]); in-place ok.
template <int COUT>
__global__ __launch_bounds__(256) void finalize_kernel(
    const float* __restrict__ hagg, const float* __restrict__ X,
    const float* __restrict__ root, const float* __restrict__ bias,
    const int* __restrict__ deg, float* __restrict__ hout, int N) {
  __shared__ float Rs[32 * COUT];
  int t = threadIdx.x;
  #pragma unroll
  for (int q = 0; q < (32 * COUT) / 1024; ++q)
    *(float4*)&Rs[(q * 256 + t) * 4] = *(const float4*)&root[(q * 256 + t) * 4];
  __syncthreads();
  constexpr int TPN = COUT / 4;
  int gid = blockIdx.x * 256 + t;
  int n = gid / TPN;
  int c0 = (gid % TPN) * 4;
  if (n >= N) return;
  const float* xr = X + (size_t)n * 32;
  float rd = 1.f / (float)max(deg[n], 1);
  float4 hv = *(const float4*)&hagg[(size_t)n * COUT + c0];
  float a0 = hv.x * rd, a1 = hv.y * rd, a2 = hv.z * rd, a3 = hv.w * rd;
  #pragma unroll
  for (int i = 0; i < 32; ++i) {
    float xv = xr[i];
    const float* rr = &Rs[i * COUT + c0];
    a0 = fmaf(xv, rr[0], a0);
    a1 = fmaf(xv, rr[1], a1);
    a2 = fmaf(xv, rr[2], a2);
    a3 = fmaf(xv, rr[3], a3);
  }
  float4 o;
  o.x = fmaxf(a0 + bias[c0 + 0], 0.f);
  o.y = fmaxf(a1 + bias[c0 + 1], 0.f);
  o.z = fmaxf(a2 + bias[c0 + 2], 0.f);
  o.w = fmaxf(a3 + bias[c0 + 3], 0.f);
  *(float4*)&hout[(size_t)n * COUT + c0] = o;
}

__global__ __launch_bounds__(256) void pool_kernel(
    const float* __restrict__ h2, const int* __restrict__ batch, int N,
    float* __restrict__ poolacc) {
  __shared__ float red[4][64];
  int g = blockIdx.x >> 2, part = blockIdx.x & 3;
  int lo = lowb(batch, N, g), hi = lowb(batch, N, g + 1);
  int len = hi - lo;
  int b0 = lo + (int)(((long long)len * part) / 4);
  int b1 = lo + (int)(((long long)len * (part + 1)) / 4);
  int r = threadIdx.x >> 6, o = threadIdx.x & 63;
  float s = 0.f;
  for (int row = b0 + r; row < b1; row += 4) s += h2[(size_t)row * 64 + o];
  red[r][o] = s;
  __syncthreads();
  if (r == 0) {
    float v = red[0][o] + red[1][o] + red[2][o] + red[3][o];
    atomicAdd(&poolacc[g * 64 + o], v);
  }
}

__global__ __launch_bounds__(64) void head_kernel(
    const float* __restrict__ poolacc, const int* __restrict__ batch, int N,
    const float* __restrict__ w1, const float* __restrict__ b1,
    const float* __restrict__ w2, const float* __restrict__ b2,
    const float* __restrict__ w3, const float* __restrict__ b3,
    float* __restrict__ out) {
  __shared__ float gb[64];
  __shared__ float lg[10];
  int g = blockIdx.x, o = threadIdx.x;
  int lo = lowb(batch, N, g), hi = lowb(batch, N, g + 1);
  float cnt = fmaxf((float)(hi - lo), 1.f);
  float gv = poolacc[g * 64 + o] / cnt;
  gb[o] = gv;
  __syncthreads();
  float tacc = b1[o];
  for (int i = 0; i < 64; ++i) tacc = fmaf(gb[i], w1[i * 64 + o], tacc);
  gv = gv * (1.f / (1.f + expf(-tacc)));
  __syncthreads(); gb[o] = gv; __syncthreads();
  tacc = b2[o];
  for (int i = 0; i < 64; ++i) tacc = fmaf(gb[i], w2[i * 64 + o], tacc);
  gv = gv * (1.f / (1.f + expf(-tacc)));
  __syncthreads(); gb[o] = gv; __syncthreads();
  if (o < 10) {
    float l = b3[o];
    for (int i = 0; i < 64; ++i) l = fmaf(gb[i], w3[i * 10 + o], l);
    lg[o] = l;
  }
  __syncthreads();
  if (o < 10) {
    float m = lg[0];
    #pragma unroll
    for (int c = 1; c < 10; ++c) m = fmaxf(m, lg[c]);
    float s = 0.f;
    #pragma unroll
    for (int c = 0; c < 10; ++c) s += expf(lg[c] - m);
    out[g * 10 + o] = lg[o] - m - logf(s);
  }
}

extern "C" void kernel_launch(void* const* d_in, const int* in_sizes, int n_in,
                              void* d_out, int out_size, void* d_ws, size_t ws_size,
                              hipStream_t stream) {
  const float* x     = (const float*)d_in[0];
  const int*   ei    = (const int*)d_in[1];
  const float* eattr = (const float*)d_in[2];
  const int*   batch = (const int*)d_in[3];
  const float* W1    = (const float*)d_in[4];
  const float* root1 = (const float*)d_in[5];
  const float* b1    = (const float*)d_in[6];
  const float* W2    = (const float*)d_in[7];
  const float* root2 = (const float*)d_in[8];
  const float* b2    = (const float*)d_in[9];
  const float* l1w   = (const float*)d_in[10];
  const float* l1b   = (const float*)d_in[11];
  const float* l2w   = (const float*)d_in[12];
  const float* l2b   = (const float*)d_in[13];
  const float* l3w   = (const float*)d_in[14];
  const float* l3b   = (const float*)d_in[15];
  float* out = (float*)d_out;

  const int N = in_sizes[0] / 32;
  const int E = in_sizes[1] / 2;
  const int Npad = (N + 63) & ~63;

  char* base = (char*)d_ws;
  size_t off = 0;
  auto walloc = [&](size_t bytes) -> void* {
    off = (off + 255) & ~(size_t)255;
    void* p = base + off;
    off += bytes;
    return p;
  };
  int*   deg     = (int*)walloc((size_t)Npad * 4);
  int*   offs    = (int*)walloc((size_t)(N + 1) * 4);
  int*   cursor  = (int*)walloc((size_t)N * 4);
  int*   bsums   = (int*)walloc(64 * 4);
  int*   boff    = (int*)walloc(64 * 4);
  float* poolacc = (float*)walloc(64 * 64 * 4);
  float* h1      = (float*)walloc((size_t)N * 32 * 4);
  float* h2      = (float*)walloc((size_t)N * 64 * 4);
  int4*  emeta   = (int4*)walloc((size_t)E * 16);
  off = (off + 255) & ~(size_t)255;
  size_t avail = (ws_size > off) ? (ws_size - off) : 0;
  __half* Yb = (__half*)(base + off);

  // i1-group sizing: buffer holds (G+1) row-groups of 5 k-rows each (fp16)
  auto pickG = [&](int cout) -> int {
    size_t g5 = (size_t)N * 5 * cout * 2;
    if (avail < 2 * g5) return 0;
    size_t G = avail / g5 - 1;
    return (int)(G > 4 ? 4 : G);
  };
  int G1 = pickG(32), G2 = pickG(64);
  if (!G1 || !G2) return;                   // insufficient workspace

  const int* srcA = ei;
  const int* dstA = ei + E;

  hipMemsetAsync(deg, 0, (size_t)Npad * 4, stream);
  hipMemsetAsync(cursor, 0, (size_t)N * 4, stream);
  hipMemsetAsync(poolacc, 0, 64 * 64 * 4, stream);

  hist_kernel<<<(E + 255) / 256, 256, 0, stream>>>(dstA, E, deg);
  int nb = (N + 1023) / 1024;
  scan_block_kernel<<<nb, 1024, 0, stream>>>(deg, N, offs, bsums);
  scan_bsums_kernel<<<1, 64, 0, stream>>>(bsums, nb, boff);
  scan_add_kernel<<<(N + 255) / 256, 256, 0, stream>>>(offs, boff, N);
  scatter_kernel<<<(E + 255) / 256, 256, 0, stream>>>(srcA, dstA, (const float2*)eattr,
                                                      E, offs, cursor, emeta);

  const int ygrid = (N + 63) / 64;
  const int ggrid = (N + 3) / 4;
  for (int layer = 0; layer < 2; ++layer) {
    const float* Xin = layer ? h1 : x;
    const float* Wl  = layer ? W2 : W1;
    const float* rl  = layer ? root2 : root1;
    const float* bl  = layer ? b2 : b1;
    float* Hout      = layer ? h2 : h1;
    const int G      = layer ? G2 : G1;
    const int COUT   = layer ? 64 : 32;
    for (int g0 = 0; g0 < 4; g0 += G) {
      int g1 = min(4, g0 + G);
      int kFirst = g0 * 5, kCount = (g1 - g0 + 1) * 5;
      int strideY = kCount * COUT;
      int first = (g0 == 0) ? 1 : 0;
      if (layer == 0) {
        ygemm_kernel<32><<<ygrid, 256, 0, stream>>>(Xin, Wl, Yb, N, kFirst, kCount, strideY);
        gather_kernel<32><<<ggrid, 256, 0, stream>>>(emeta, offs, Yb, strideY,
                                                     Hout, N, g0, g1, first);
      } else {
        ygemm_kernel<64><<<ygrid, 256, 0, stream>>>(Xin, Wl, Yb, N, kFirst, kCount, strideY);
        gather_kernel<64><<<ggrid, 256, 0, stream>>>(emeta, offs, Yb, strideY,
                                                     Hout, N, g0, g1, first);
      }
    }
    if (layer == 0)
      finalize_kernel<32><<<((size_t)N * 8 + 255) / 256, 256, 0, stream>>>(
          Hout, Xin, rl, bl, deg, Hout, N);
    else
      finalize_kernel<64><<<((size_t)N * 16 + 255) / 256, 256, 0, stream>>>(
          Hout, Xin, rl, bl, deg, Hout, N);
  }
  pool_kernel<<<256, 256, 0, stream>>>(h2, batch, N, poolacc);
  head_kernel<<<64, 64, 0, stream>>>(poolacc, batch, N,
                                     l1w, l1b, l2w, l2b, l3w, l3b, out);
}